// Round 7
// baseline (1101.930 us; speedup 1.0000x reference)
//
#include <hip/hip_runtime.h>
#include <cstddef>

// ---------------- problem constants ----------------
#define NB 16
#define NC 256
#define NH 32
#define NW 32
#define NK 81

// ---- LDS float offsets (total 19440 floats = 77,760 B -> 2 blocks/CU) ----
#define L_FG    0        // [256][36] filter-grad (corr part, then +reg term)
#define L_MRES  9216     // [81][36]  mapped residuals; pass C reuses as sg^2
#define L_FS    12132    // A/C: [16ch][9dy][44]=6336 ; B: [128ch][44]=5632 ; scores 2x[81][36]
#define L_CB    18468    // [16][36] A-operand chunk buf; B reuses as anum partials [8][36]
#define L_SIGN  19044    // uchar[324] score sign bits
#define L_CL    19128    // cst copy [245]
#define L_ANUM  19376    // [32]
#define L_ALPHA 19408    // [32]
#define L_TOT   19440
#define SB1     (L_FS + 2916)   // second score buffer

__device__ __forceinline__ float4 ld4(const float* p) { return *reinterpret_cast<const float4*>(p); }
__device__ __forceinline__ void st4(float* p, float4 v) { *reinterpret_cast<float4*>(p) = v; }

__device__ __forceinline__ void map_by(int bi, int& b, int& y) {
    int xcd = bi & 7, slot = bi >> 3;
    b = xcd * 2 + (slot >> 5);
    y = slot & 31;
}

// ---------------- constants / distance map (cst = ws[0..]) ----------------
__global__ void k_const(const float* lw, const float* mw, const float* sww,
                        const float* lsl, const float* fr, float* cst) {
    int tid = threadIdx.x;
    if (tid < 81) {
        int dy = tid / 9, dx = tid % 9;
        float dist = sqrtf((float)((dy - 4) * (dy - 4) + (dx - 4) * (dx - 4)));
        float lab = 0.f, mm = 0.f, ss = 0.f;
        for (int d = 0; d < 10; d++) {
            float diff = dist * 2.f - (float)d;
            float bv = (d < 9) ? fmaxf(0.f, 1.f - fabsf(diff))
                               : fminf(fmaxf(1.f + diff, 0.f), 1.f);
            lab += bv * lw[d];
            mm  += bv * mw[d];
            ss  += bv * sww[d];
        }
        cst[tid]       = lab;
        cst[81 + tid]  = 1.f / (1.f + expf(-mm));
        cst[162 + tid] = ss;
    } else if (tid == 81) {
        cst[243] = expf(lsl[0]);
    } else if (tid == 82) {
        cst[244] = fmaxf(fr[0] * fr[0], 1e-10f) * (1.f / 65536.f);
    } else if (tid >= 83 && tid < 89) {
        cst[245 + (tid - 83)] = 0.f;
    }
}

// ---------------- copy flt input -> d_out (working filter lives in out) ----------------
__global__ void k_copy(const float* __restrict__ src, float* __restrict__ dst) {
    int i = (blockIdx.x * 256 + threadIdx.x) * 4;
    st4(dst + i, ld4(src + i));
}

// ---- A/C correlation pass: acc[dx][4px] over 16 chunks of 16 channels ----
// isA: stage A-operand (flt) from global into L_CB per chunk; else operand = L_FG.
__device__ __forceinline__ void corr_pass16(float* S, const float* __restrict__ feat,
                                            const float* __restrict__ flt_g, bool isA,
                                            int b, int y, int tid, int g, int dyA, int octA,
                                            float acc[9][4]) {
    // stage mapping: items i = tid, tid+576 over 1152 = 16c x 9dy x 8q
    const float* sgp[2]; float* sfp[2]; bool sval[2];
#pragma unroll
    for (int k = 0; k < 2; k++) {
        int i = tid + 576 * k;
        int r = i >> 3, q = i & 7;
        int c = r / 9, dy = r - 9 * c;
        int ry = y + dy - 4;
        sval[k] = (ry >= 0 && ry < 32);
        sgp[k] = feat + (((size_t)(b * NC + c)) * NH + (sval[k] ? ry : 0)) * NW + q * 4;
        sfp[k] = S + L_FS + c * 396 + dy * 44 + 4 + q * 4;
    }
    const bool cbv = isA && (tid < 128);
    const float* cgp = flt_g + (((size_t)(b * NC + (tid >> 3))) * NH + y) * NW + (tid & 7) * 4;
    float* cfp = S + L_CB + (tid >> 3) * 36 + (tid & 7) * 4;

    // zero fs (OOB rows + halos stay zero)
    const float4 z4 = make_float4(0.f, 0.f, 0.f, 0.f);
    for (int i = tid; i < 1584; i += 576) st4(S + L_FS + i * 4, z4);

#pragma unroll
    for (int dx = 0; dx < 9; dx++)
#pragma unroll
        for (int i = 0; i < 4; i++) acc[dx][i] = 0.f;

    float4 R[2], Rcb;
#pragma unroll
    for (int k = 0; k < 2; k++) if (sval[k]) R[k] = ld4(sgp[k]);
    if (cbv) Rcb = ld4(cgp);
    __syncthreads();

#pragma unroll 1
    for (int chunk = 0; chunk < 16; chunk++) {
#pragma unroll
        for (int k = 0; k < 2; k++) if (sval[k]) st4(sfp[k], R[k]);
        if (cbv) st4(cfp, Rcb);
        __syncthreads();
        if (chunk < 15) {
            int off = (chunk + 1) * 16384;   // 16 ch * 1024 floats
#pragma unroll
            for (int k = 0; k < 2; k++) if (sval[k]) R[k] = ld4(sgp[k] + off);
            if (cbv) Rcb = ld4(cgp + off);
        }
        const float* opp = isA ? (S + L_CB) : (S + L_FG + chunk * 576);
#pragma unroll
        for (int j = 0; j < 2; j++) {
            int cl = g * 2 + j;
            float4 o = ld4(opp + cl * 36 + octA * 4);
            const float* wb = S + L_FS + cl * 396 + dyA * 44 + octA * 4;
            float4 w0 = ld4(wb), w1 = ld4(wb + 4), w2 = ld4(wb + 8);
            float w[12] = {w0.x, w0.y, w0.z, w0.w, w1.x, w1.y, w1.z, w1.w,
                           w2.x, w2.y, w2.z, w2.w};
            float ov[4] = {o.x, o.y, o.z, o.w};
#pragma unroll
            for (int dx = 0; dx < 9; dx++)
#pragma unroll
                for (int i = 0; i < 4; i++)
                    acc[dx][i] = fmaf(ov[i], w[dx + i], acc[dx][i]);
        }
        __syncthreads();
    }
}

// ---- cross-group reduce: 8 groups -> 2 score buffers (4 phases) ----
__device__ __forceinline__ void reduce8(float* S, int g, int dyA, int octA, float acc[9][4]) {
#pragma unroll 1
    for (int p = 0; p < 4; p++) {
        if ((g & 3) == p) {
            float* B = S + L_FS + (g >> 2) * 2916;
#pragma unroll
            for (int dx = 0; dx < 9; dx++) {
                int idx = (dyA * 9 + dx) * 36 + octA * 4;
                if (p == 0) {
                    st4(B + idx, make_float4(acc[dx][0], acc[dx][1], acc[dx][2], acc[dx][3]));
                } else {
                    float4 t = ld4(B + idx);
                    t.x += acc[dx][0]; t.y += acc[dx][1]; t.z += acc[dx][2]; t.w += acc[dx][3];
                    st4(B + idx, t);
                }
            }
        }
        __syncthreads();
    }
}

// ---------------- mega kernel: one block = one (b,y) row, 3 iterations ----------------
__global__ __launch_bounds__(576, 5) void mega(const float* __restrict__ feat,
                                               float* __restrict__ flt_g,   // = out
                                               float* __restrict__ cst_g) {
    __shared__ float S[L_TOT];
    int b, y; map_by(blockIdx.x, b, y);
    const int tid = threadIdx.x;

    // A/C compute mapping: 8 groups x (9 dy x 8 oct(4px))
    const int g = tid / 72, s72 = tid - g * 72;
    const int dyA = s72 >> 3, octA = s72 & 7;
    // B mapping
    const bool actB = tid < 512;
    const int c_l = tid & 63, octB = tid >> 6;   // octB 0..7 (4 px)

    for (int i = tid; i < 245; i += 576) S[L_CL + i] = cst_g[i];
    __syncthreads();
    const float step = S[L_CL + 243];
    const float rw   = S[L_CL + 244];
    const float4 z4 = make_float4(0.f, 0.f, 0.f, 0.f);

#pragma unroll 1
    for (int it = 0; it < 3; it++) {
        // ================= pass A =================
        float acc[9][4];
        corr_pass16(S, feat, flt_g, true, b, y, tid, g, dyA, octA, acc);
        reduce8(S, g, dyA, octA, acc);

        float srcl = 0.f;
        if (tid < 324) {
            int k = tid >> 2, o8 = (tid & 3) * 8;
            float lab = S[L_CL + k], m = S[L_CL + 81 + k], sw = S[L_CL + 162 + k];
            float am = 0.5f * (1.f - m), ap = 0.5f * (1.f + m);
            unsigned char sb = 0;
#pragma unroll
            for (int h = 0; h < 2; h++) {
                int idx = k * 36 + o8 + h * 4;
                float4 a0 = ld4(S + L_FS + idx), a1 = ld4(S + SB1 + idx);
                float sv[4] = {a0.x + a1.x, a0.y + a1.y, a0.z + a1.z, a0.w + a1.w};
                float tr[4];
#pragma unroll
                for (int xi = 0; xi < 4; xi++) {
                    float s = sv[xi];
                    float act = am * fabsf(s) + ap * s;
                    float sgn = (s > 0.f ? 1.f : 0.f) - (s < 0.f ? 1.f : 0.f);
                    float msk = am * sgn + ap;
                    float lres = sw * (act - lab);
                    srcl = fmaf(lres, lres, srcl);
                    tr[xi] = msk * sw * lres;
                    if (s > 0.f) sb |= (unsigned char)(1u << (h * 4 + xi));
                }
                st4(S + L_MRES + idx, make_float4(tr[0], tr[1], tr[2], tr[3]));
            }
            ((unsigned char*)(S + L_SIGN))[k * 4 + (tid & 3)] = sb;
        }
#pragma unroll
        for (int off = 32; off > 0; off >>= 1) srcl += __shfl_down(srcl, off, 64);
        if ((tid & 63) == 0) atomicAdd(cst_g + 245 + it, srcl);
        __syncthreads();

        // ================= pass B =================
        {
            float accB[2][2][4];
#pragma unroll
            for (int a = 0; a < 2; a++)
#pragma unroll
                for (int j = 0; j < 2; j++)
#pragma unroll
                    for (int i = 0; i < 4; i++) accB[a][j][i] = 0.f;

            // halo zeros for fs [128][44]
            if (tid < 256) st4(S + L_FS + (tid >> 1) * 44 + (tid & 1) * 40, z4);

            // stage mapping: items i = tid, tid+576 over 1024 = 128c x 8q
            const float* bgp[2]; float* bfp[2]; bool bval[2];
#pragma unroll
            for (int k = 0; k < 2; k++) {
                int i = tid + 576 * k;
                bval[k] = i < 1024;
                int c = (i >> 3) & 127, q = i & 7;
                bgp[k] = feat + ((size_t)(b * NC + c)) * (NH * NW) + q * 4;
                bfp[k] = S + L_FS + c * 44 + 4 + q * 4;
            }
            // first valid phase (validity depends only on dy -> p0 is even)
            int p0 = 0;
            while (p0 < 18) { int ry = y + (p0 >> 1) - 4; if (ry >= 0 && ry < 32) break; p0++; }
            float4 RB[2];
            {
                int cg = p0 & 1, ry = y + (p0 >> 1) - 4;
#pragma unroll
                for (int k = 0; k < 2; k++)
                    if (bval[k]) RB[k] = ld4(bgp[k] + cg * 131072 + ry * 32);
            }
            __syncthreads();

            float rr[9][4];
#pragma unroll 1
            for (int p = p0; p < 18; p++) {
                int dy = p >> 1, cg = p & 1, ry = y + dy - 4;
                if (ry < 0 || ry >= 32) continue;       // block-uniform
#pragma unroll
                for (int k = 0; k < 2; k++) if (bval[k]) st4(bfp[k], RB[k]);
                __syncthreads();
                int pn = p + 1;
                while (pn < 18) { int ryn = y + (pn >> 1) - 4; if (ryn >= 0 && ryn < 32) break; pn++; }
                if (pn < 18) {
                    int cgn = pn & 1, ryn = y + (pn >> 1) - 4;
#pragma unroll
                    for (int k = 0; k < 2; k++)
                        if (bval[k]) RB[k] = ld4(bgp[k] + cgn * 131072 + ryn * 32);
                }
                if (actB) {
                    if (cg == 0) {
#pragma unroll
                        for (int dx = 0; dx < 9; dx++) {
                            float4 t = ld4(S + L_MRES + (dy * 9 + dx) * 36 + octB * 4);
                            rr[dx][0] = t.x; rr[dx][1] = t.y; rr[dx][2] = t.z; rr[dx][3] = t.w;
                        }
                    }
#pragma unroll
                    for (int j = 0; j < 2; j++) {
                        const float* wb = S + L_FS + (c_l * 2 + j) * 44 + octB * 4;
                        float4 w0 = ld4(wb), w1 = ld4(wb + 4), w2 = ld4(wb + 8);
                        float w[12] = {w0.x, w0.y, w0.z, w0.w, w1.x, w1.y, w1.z, w1.w,
                                       w2.x, w2.y, w2.z, w2.w};
#pragma unroll
                        for (int dx = 0; dx < 9; dx++)
#pragma unroll
                            for (int i = 0; i < 4; i++)
                                accB[cg][j][i] = fmaf(rr[dx][i], w[dx + i], accB[cg][j][i]);
                    }
                }
                __syncthreads();
            }
            // corr part -> L_FG
            if (actB) {
#pragma unroll
                for (int cg = 0; cg < 2; cg++)
#pragma unroll
                    for (int j = 0; j < 2; j++)
                        st4(S + L_FG + (cg * 128 + c_l * 2 + j) * 36 + octB * 4,
                            make_float4(accB[cg][j][0], accB[cg][j][1],
                                        accB[cg][j][2], accB[cg][j][3]));
            }
            __syncthreads();
            // fg += rw*flt (flt from global, coalesced); reg loss
            float regl = 0.f;
            for (int i = tid; i < 2048; i += 576) {
                int c = i >> 3, q = i & 7;
                float4 fl = ld4(flt_g + (((size_t)(b * NC + c)) * NH + y) * NW + q * 4);
                float4 fc = ld4(S + L_FG + c * 36 + q * 4);
                fc.x += rw * fl.x; fc.y += rw * fl.y; fc.z += rw * fl.z; fc.w += rw * fl.w;
                regl += fl.x * fl.x + fl.y * fl.y + fl.z * fl.z + fl.w * fl.w;
                st4(S + L_FG + c * 36 + q * 4, fc);
            }
#pragma unroll
            for (int off = 32; off > 0; off >>= 1) regl += __shfl_down(regl, off, 64);
            if ((tid & 63) == 0) atomicAdd(cst_g + 248 + it, regl);
            __syncthreads();
            // alpha_num = sum_c fg^2 : partials in L_CB [8][36]
            if (tid < 256) {
                int x = tid & 31, c8 = tid >> 5;
                float s = 0.f;
                for (int cc = 0; cc < 32; cc++) {
                    float v = S[L_FG + (c8 * 32 + cc) * 36 + x];
                    s = fmaf(v, v, s);
                }
                S[L_CB + c8 * 36 + x] = s;
            }
            __syncthreads();
            if (tid < 32) {
                float s = 0.f;
#pragma unroll
                for (int k = 0; k < 8; k++) s += S[L_CB + k * 36 + tid];
                S[L_ANUM + tid] = s;
            }
            __syncthreads();
        }

        // ================= pass C =================
        float accC[9][4];
        corr_pass16(S, feat, flt_g, false, b, y, tid, g, dyA, octA, accC);
        reduce8(S, g, dyA, octA, accC);

        if (tid < 324) {
            int k = tid >> 2, o8 = (tid & 3) * 8;
            float m = S[L_CL + 81 + k], sw = S[L_CL + 162 + k];
            float am = 0.5f * (1.f - m), ap = 0.5f * (1.f + m);
            unsigned char sb = ((unsigned char*)(S + L_SIGN))[k * 4 + (tid & 3)];
#pragma unroll
            for (int h = 0; h < 2; h++) {
                int idx = k * 36 + o8 + h * 4;
                float4 a0 = ld4(S + L_FS + idx), a1 = ld4(S + SB1 + idx);
                float sv[4] = {a0.x + a1.x, a0.y + a1.y, a0.z + a1.z, a0.w + a1.w};
                float sq[4];
#pragma unroll
                for (int xi = 0; xi < 4; xi++) {
                    float sgn = (sb & (1u << (h * 4 + xi))) ? 1.f : -1.f;
                    float msk = am * sgn + ap;
                    float sg = sw * msk * sv[xi];
                    sq[xi] = sg * sg;
                }
                st4(S + L_MRES + idx, make_float4(sq[0], sq[1], sq[2], sq[3]));
            }
        }
        __syncthreads();
        if (tid < 32) {
            float den = 0.f;
            for (int k = 0; k < 81; k++) den += S[L_MRES + k * 36 + tid];
            float num = S[L_ANUM + tid];
            float dd = fmaxf(den + rw * num, 1e-8f);
            S[L_ALPHA + tid] = step * num / dd;
        }
        __syncthreads();
        // update: flt(global) -= alpha * fg
        for (int i = tid; i < 2048; i += 576) {
            int c = i >> 3, q = i & 7;
            size_t go = (((size_t)(b * NC + c)) * NH + y) * NW + q * 4;
            float4 fl = ld4(flt_g + go);
            float4 fg = ld4(S + L_FG + c * 36 + q * 4);
            fl.x -= S[L_ALPHA + q * 4 + 0] * fg.x;
            fl.y -= S[L_ALPHA + q * 4 + 1] * fg.y;
            fl.z -= S[L_ALPHA + q * 4 + 2] * fg.z;
            fl.w -= S[L_ALPHA + q * 4 + 3] * fg.w;
            st4(flt_g + go, fl);
        }
        __syncthreads();
    }
}

// ---------------- tail: write tr, tr_src, tr_reg ----------------
__global__ void k_tail(const float* cst, float* out) {
    int i = threadIdx.x;
    if (i < 3) {
        float rw = cst[244];
        float src = 0.5f * cst[245 + i] / 16.f;
        float reg = 0.5f * rw * cst[248 + i] / 16.f;
        out[4194304 + i] = src + reg;
        out[4194307 + i] = src;
        out[4194310 + i] = reg;
    }
}

extern "C" void kernel_launch(void* const* d_in, const int* in_sizes, int n_in,
                              void* d_out, int out_size, void* d_ws, size_t ws_size,
                              hipStream_t stream) {
    (void)in_sizes; (void)n_in; (void)out_size; (void)ws_size;
    const float* flt_in = (const float*)d_in[0];
    const float* feat   = (const float*)d_in[1];
    const float* lw     = (const float*)d_in[2];
    const float* mw     = (const float*)d_in[3];
    const float* sww    = (const float*)d_in[4];
    const float* lsl    = (const float*)d_in[5];
    const float* fr     = (const float*)d_in[6];
    float* out = (float*)d_out;
    float* cst = (float*)d_ws;

    k_const<<<1, 128, 0, stream>>>(lw, mw, sww, lsl, fr, cst);
    k_copy<<<4096, 256, 0, stream>>>(flt_in, out);   // working filter lives in out
    mega<<<512, 576, 0, stream>>>(feat, out, cst);
    k_tail<<<1, 64, 0, stream>>>(cst, out);
}